// Round 10
// baseline (302.217 us; speedup 1.0000x reference)
//
#include <hip/hip_runtime.h>
#include <hip/hip_cooperative_groups.h>
#include <math.h>

#define H 1024
#define T 4096
#define B 16

namespace cg = cooperative_groups;

typedef float f4 __attribute__((ext_vector_type(4)));

// ---------------- Cooperative fused kernel ----------------
// 1024 blocks x 256 thr, 4 blocks/CU co-resident (launch_bounds(256,4):
// VGPR cap 128 — actual use far below; 4.2 KiB LDS). grid.sync() replaces
// the two inter-kernel launch gaps.
__global__ void __launch_bounds__(256, 4) fused_all(
    const float* __restrict__ dec, const float* __restrict__ enc,
    const float* __restrict__ W, float* __restrict__ v,
    float* __restrict__ scores, float* __restrict__ out)
{
    cg::grid_group grid = cg::this_grid();
    const int tid = threadIdx.x;
    const int bid = blockIdx.x;

    __shared__ f4 red[256];
    __shared__ float redm[4];
    __shared__ float reds[4];

    // ---- Phase 1: v = dec^T @ W (blocks 0..511, R7 proj shape) ----
    if (bid < 512) {
        int b      = bid >> 5;
        int htile  = bid & 31;
        int h4     = tid & 7;
        int dc     = tid >> 3;
        int h4base = htile * 8;

        const f4* Wp = (const f4*)W;
        f4 acc = {0.f, 0.f, 0.f, 0.f};
        int d0 = dc * 32;
        #pragma unroll 8
        for (int i = 0; i < 32; ++i) {
            int d = d0 + i;
            float s = dec[d * B + b];
            acc += s * Wp[d * (H / 4) + h4base + h4];
        }
        red[tid] = acc;
        __syncthreads();
        #pragma unroll
        for (int s = 16; s > 0; s >>= 1) {
            if (dc < s) {
                f4 m = red[dc * 8 + h4] + red[(dc + s) * 8 + h4];
                red[dc * 8 + h4] = m;
            }
            __syncthreads();
        }
        if (dc == 0)
            ((f4*)(v + b * H))[h4base + h4] = red[h4];
    }

    grid.sync();

    // ---- Phase 2: scores. 4096 waves; each wave does 16 CONTIGUOUS rows
    // strictly sequentially (unroll 1: R3's proven one-row burst, iterated;
    // not R4/R7's widened simultaneous footprint). ----
    {
        int wave = (bid * 256 + tid) >> 6;   // 0..4095
        int lane = tid & 63;
        #pragma unroll 1
        for (int j = 0; j < 16; ++j) {
            int r = wave * 16 + j;           // linear row = t*B + b
            int b = r & (B - 1);
            int t = r >> 4;
            const f4* ep = (const f4*)enc + (size_t)r * (H / 4) + lane;
            const f4* vp = (const f4*)(v + b * H) + lane;
            float acc = 0.f;
            #pragma unroll
            for (int i = 0; i < 4; ++i) {
                f4 e = __builtin_nontemporal_load(ep + i * 64);
                f4 w = vp[i * 64];
                acc = fmaf(e.x, w.x, acc);
                acc = fmaf(e.y, w.y, acc);
                acc = fmaf(e.z, w.z, acc);
                acc = fmaf(e.w, w.w, acc);
            }
            #pragma unroll
            for (int off = 32; off > 0; off >>= 1)
                acc += __shfl_down(acc, off);
            if (lane == 0) scores[(size_t)b * T + t] = acc;
        }
    }

    grid.sync();

    // ---- Phase 3: row softmax, blocks 0..15 ----
    if (bid < B) {
        int b = bid;
        int lane = tid & 63;
        int wid = tid >> 6;
        const f4* rp = (const f4*)(scores + (size_t)b * T);
        f4 vals[4];
        float m = -INFINITY;
        #pragma unroll
        for (int i = 0; i < 4; ++i) {
            vals[i] = rp[tid + i * 256];
            m = fmaxf(m, fmaxf(fmaxf(vals[i].x, vals[i].y), fmaxf(vals[i].z, vals[i].w)));
        }
        #pragma unroll
        for (int off = 32; off > 0; off >>= 1)
            m = fmaxf(m, __shfl_xor(m, off));
        if (lane == 0) redm[wid] = m;
        __syncthreads();
        m = fmaxf(fmaxf(redm[0], redm[1]), fmaxf(redm[2], redm[3]));

        float s = 0.f;
        #pragma unroll
        for (int i = 0; i < 4; ++i) {
            vals[i].x = __expf(vals[i].x - m);
            vals[i].y = __expf(vals[i].y - m);
            vals[i].z = __expf(vals[i].z - m);
            vals[i].w = __expf(vals[i].w - m);
            s += vals[i].x + vals[i].y + vals[i].z + vals[i].w;
        }
        #pragma unroll
        for (int off = 32; off > 0; off >>= 1)
            s += __shfl_xor(s, off);
        if (lane == 0) reds[wid] = s;
        __syncthreads();
        float inv = 1.f / (reds[0] + reds[1] + reds[2] + reds[3]);

        f4* op = (f4*)(out + (size_t)b * T);
        #pragma unroll
        for (int i = 0; i < 4; ++i) {
            f4 rr = vals[i] * inv;
            __builtin_nontemporal_store(rr, op + tid + i * 256);
        }
    }
}

// ---------------- Fallback 3-kernel path (proven R7, 52.3 us) ----------------
__global__ void __launch_bounds__(256) proj_vec_kernel(
    const float* __restrict__ dec, const float* __restrict__ W,
    float* __restrict__ v)
{
    int b      = blockIdx.x >> 5;
    int htile  = blockIdx.x & 31;
    int h4     = threadIdx.x & 7;
    int dc     = threadIdx.x >> 3;
    int h4base = htile * 8;

    const f4* Wp = (const f4*)W;
    f4 acc = {0.f, 0.f, 0.f, 0.f};
    int d0 = dc * 32;
    #pragma unroll 8
    for (int i = 0; i < 32; ++i) {
        int d = d0 + i;
        float s = dec[d * B + b];
        acc += s * Wp[d * (H / 4) + h4base + h4];
    }
    __shared__ f4 red[256];
    red[threadIdx.x] = acc;
    __syncthreads();
    #pragma unroll
    for (int s = 16; s > 0; s >>= 1) {
        if (dc < s) {
            f4 m = red[dc * 8 + h4] + red[(dc + s) * 8 + h4];
            red[dc * 8 + h4] = m;
        }
        __syncthreads();
    }
    if (dc == 0)
        ((f4*)(v + b * H))[h4base + h4] = red[h4];
}

__global__ void __launch_bounds__(256) scores_kernel(
    const float* __restrict__ v, const float* __restrict__ enc,
    float* __restrict__ scores)
{
    int wave = (int)((blockIdx.x * 256u + threadIdx.x) >> 6);
    int lane = threadIdx.x & 63;
    int b = wave & (B - 1);
    int t = wave >> 4;
    const f4* ep = (const f4*)(enc + (size_t)t * (B * H) + (size_t)b * H);
    const f4* vp = (const f4*)(v + b * H);
    float acc = 0.f;
    #pragma unroll
    for (int i = 0; i < 4; ++i) {
        f4 e = __builtin_nontemporal_load(&ep[lane + i * 64]);
        f4 w = vp[lane + i * 64];
        acc = fmaf(e.x, w.x, acc);
        acc = fmaf(e.y, w.y, acc);
        acc = fmaf(e.z, w.z, acc);
        acc = fmaf(e.w, w.w, acc);
    }
    #pragma unroll
    for (int off = 32; off > 0; off >>= 1)
        acc += __shfl_down(acc, off);
    if (lane == 0) scores[b * T + t] = acc;
}

__global__ void __launch_bounds__(1024) softmax_kernel(
    const float* __restrict__ scores, float* __restrict__ out)
{
    int b = blockIdx.x;
    int tid = threadIdx.x;
    int wid = tid >> 6;
    int lane = tid & 63;
    __shared__ float redm[16];
    __shared__ float reds[16];

    const f4* rp = (const f4*)(scores + (size_t)b * T);
    f4 x = rp[tid];

    float m = fmaxf(fmaxf(x.x, x.y), fmaxf(x.z, x.w));
    #pragma unroll
    for (int off = 32; off > 0; off >>= 1)
        m = fmaxf(m, __shfl_xor(m, off));
    if (lane == 0) redm[wid] = m;
    __syncthreads();
    m = redm[0];
    #pragma unroll
    for (int i = 1; i < 16; ++i) m = fmaxf(m, redm[i]);

    x.x = __expf(x.x - m);
    x.y = __expf(x.y - m);
    x.z = __expf(x.z - m);
    x.w = __expf(x.w - m);
    float s = x.x + x.y + x.z + x.w;
    #pragma unroll
    for (int off = 32; off > 0; off >>= 1)
        s += __shfl_xor(s, off);
    if (lane == 0) reds[wid] = s;
    __syncthreads();
    s = reds[0];
    #pragma unroll
    for (int i = 1; i < 16; ++i) s += reds[i];
    float inv = 1.f / s;

    f4 r = x * inv;
    __builtin_nontemporal_store(r, (f4*)(out + (size_t)b * T) + tid);
}

extern "C" void kernel_launch(void* const* d_in, const int* in_sizes, int n_in,
                              void* d_out, int out_size, void* d_ws, size_t ws_size,
                              hipStream_t stream)
{
    const float* dec = (const float*)d_in[0];   // [H, B]
    const float* enc = (const float*)d_in[1];   // [T, B, H]
    const float* W   = (const float*)d_in[2];   // [H, H]
    float* out = (float*)d_out;                 // [B, T]

    float* v      = (float*)d_ws;               // B*H floats
    float* scores = v + B * H;                  // B*T floats

    void* args[] = {(void*)&dec, (void*)&enc, (void*)&W,
                    (void*)&v, (void*)&scores, (void*)&out};
    hipError_t err = hipLaunchCooperativeKernel(
        (const void*)fused_all, dim3(1024), dim3(256), args, 0, stream);

    if (err != hipSuccess) {
        // Deterministic fallback: proven 3-kernel path (52.3 us).
        proj_vec_kernel<<<512, 256, 0, stream>>>(dec, W, v);
        scores_kernel<<<(T * B) / 4, 256, 0, stream>>>(v, enc, scores);
        softmax_kernel<<<B, 1024, 0, stream>>>(scores, out);
    }
}

// Round 11
// 284.143 us; speedup vs baseline: 1.0636x; 1.0636x over previous
//
#include <hip/hip_runtime.h>
#include <hip/hip_cooperative_groups.h>
#include <math.h>

#define H 1024
#define T 4096
#define B 16

namespace cg = cooperative_groups;

typedef float f4 __attribute__((ext_vector_type(4)));

// Cooperative fused kernel: 1024 blocks x 256 thr, 4 blocks/CU co-resident
// (VGPR 36, 4.6 KiB LDS). grid.sync() replaces the two launch gaps.
// Phase-2 row ordering: r = j*NWAVES + wave, so at each round the 4096
// concurrent waves read one CONTIGUOUS 16 MB window (adjacent 4 KiB rows),
// spreading across all HBM channels — the R10 failure was the transposed
// mapping (wave*16+j), which put concurrent accesses 64 KiB apart and
// collapsed effective BW to ~0.9 TB/s.
__global__ void __launch_bounds__(256, 4) fused_all(
    const float* __restrict__ dec, const float* __restrict__ enc,
    const float* __restrict__ W, float* __restrict__ v,
    float* __restrict__ scores, float* __restrict__ out)
{
    cg::grid_group grid = cg::this_grid();
    const int tid = threadIdx.x;
    const int bid = blockIdx.x;

    __shared__ f4 red[256];
    __shared__ float redm[4];
    __shared__ float reds[4];

    // ---- Phase 1: v = dec^T @ W (blocks 0..511, R7 proj shape) ----
    if (bid < 512) {
        int b      = bid >> 5;
        int htile  = bid & 31;
        int h4     = tid & 7;
        int dc     = tid >> 3;
        int h4base = htile * 8;

        const f4* Wp = (const f4*)W;
        f4 acc = {0.f, 0.f, 0.f, 0.f};
        int d0 = dc * 32;
        #pragma unroll 8
        for (int i = 0; i < 32; ++i) {
            int d = d0 + i;
            float s = dec[d * B + b];
            acc += s * Wp[d * (H / 4) + h4base + h4];
        }
        red[tid] = acc;
        __syncthreads();
        #pragma unroll
        for (int s = 16; s > 0; s >>= 1) {
            if (dc < s) {
                f4 m = red[dc * 8 + h4] + red[(dc + s) * 8 + h4];
                red[dc * 8 + h4] = m;
            }
            __syncthreads();
        }
        if (dc == 0)
            ((f4*)(v + b * H))[h4base + h4] = red[h4];
    }

    grid.sync();

    // ---- Phase 2: scores. 16 rounds; round j covers rows
    // [j*4096, (j+1)*4096) — contiguous 16 MB across the device. ----
    {
        int wave = (bid * 256 + tid) >> 6;   // 0..4095
        int lane = tid & 63;
        #pragma unroll 1
        for (int j = 0; j < 16; ++j) {
            int r = j * 4096 + wave;         // linear row = t*B + b
            int b = r & (B - 1);
            int t = r >> 4;
            const f4* ep = (const f4*)enc + (size_t)r * (H / 4) + lane;
            const f4* vp = (const f4*)(v + b * H) + lane;
            float acc = 0.f;
            #pragma unroll
            for (int i = 0; i < 4; ++i) {
                f4 e = __builtin_nontemporal_load(ep + i * 64);
                f4 w = vp[i * 64];
                acc = fmaf(e.x, w.x, acc);
                acc = fmaf(e.y, w.y, acc);
                acc = fmaf(e.z, w.z, acc);
                acc = fmaf(e.w, w.w, acc);
            }
            #pragma unroll
            for (int off = 32; off > 0; off >>= 1)
                acc += __shfl_down(acc, off);
            if (lane == 0) scores[(size_t)b * T + t] = acc;
        }
    }

    grid.sync();

    // ---- Phase 3: row softmax, blocks 0..15 ----
    if (bid < B) {
        int b = bid;
        int lane = tid & 63;
        int wid = tid >> 6;
        const f4* rp = (const f4*)(scores + (size_t)b * T);
        f4 vals[4];
        float m = -INFINITY;
        #pragma unroll
        for (int i = 0; i < 4; ++i) {
            vals[i] = rp[tid + i * 256];
            m = fmaxf(m, fmaxf(fmaxf(vals[i].x, vals[i].y), fmaxf(vals[i].z, vals[i].w)));
        }
        #pragma unroll
        for (int off = 32; off > 0; off >>= 1)
            m = fmaxf(m, __shfl_xor(m, off));
        if (lane == 0) redm[wid] = m;
        __syncthreads();
        m = fmaxf(fmaxf(redm[0], redm[1]), fmaxf(redm[2], redm[3]));

        float s = 0.f;
        #pragma unroll
        for (int i = 0; i < 4; ++i) {
            vals[i].x = __expf(vals[i].x - m);
            vals[i].y = __expf(vals[i].y - m);
            vals[i].z = __expf(vals[i].z - m);
            vals[i].w = __expf(vals[i].w - m);
            s += vals[i].x + vals[i].y + vals[i].z + vals[i].w;
        }
        #pragma unroll
        for (int off = 32; off > 0; off >>= 1)
            s += __shfl_xor(s, off);
        if (lane == 0) reds[wid] = s;
        __syncthreads();
        float inv = 1.f / (reds[0] + reds[1] + reds[2] + reds[3]);

        f4* op = (f4*)(out + (size_t)b * T);
        #pragma unroll
        for (int i = 0; i < 4; ++i) {
            f4 rr = vals[i] * inv;
            __builtin_nontemporal_store(rr, op + tid + i * 256);
        }
    }
}

// ---------------- Fallback 3-kernel path (proven R7, 52.3 us) ----------------
__global__ void __launch_bounds__(256) proj_vec_kernel(
    const float* __restrict__ dec, const float* __restrict__ W,
    float* __restrict__ v)
{
    int b      = blockIdx.x >> 5;
    int htile  = blockIdx.x & 31;
    int h4     = threadIdx.x & 7;
    int dc     = threadIdx.x >> 3;
    int h4base = htile * 8;

    const f4* Wp = (const f4*)W;
    f4 acc = {0.f, 0.f, 0.f, 0.f};
    int d0 = dc * 32;
    #pragma unroll 8
    for (int i = 0; i < 32; ++i) {
        int d = d0 + i;
        float s = dec[d * B + b];
        acc += s * Wp[d * (H / 4) + h4base + h4];
    }
    __shared__ f4 red[256];
    red[threadIdx.x] = acc;
    __syncthreads();
    #pragma unroll
    for (int s = 16; s > 0; s >>= 1) {
        if (dc < s) {
            f4 m = red[dc * 8 + h4] + red[(dc + s) * 8 + h4];
            red[dc * 8 + h4] = m;
        }
        __syncthreads();
    }
    if (dc == 0)
        ((f4*)(v + b * H))[h4base + h4] = red[h4];
}

__global__ void __launch_bounds__(256) scores_kernel(
    const float* __restrict__ v, const float* __restrict__ enc,
    float* __restrict__ scores)
{
    int wave = (int)((blockIdx.x * 256u + threadIdx.x) >> 6);
    int lane = threadIdx.x & 63;
    int b = wave & (B - 1);
    int t = wave >> 4;
    const f4* ep = (const f4*)(enc + (size_t)t * (B * H) + (size_t)b * H);
    const f4* vp = (const f4*)(v + b * H);
    float acc = 0.f;
    #pragma unroll
    for (int i = 0; i < 4; ++i) {
        f4 e = __builtin_nontemporal_load(&ep[lane + i * 64]);
        f4 w = vp[lane + i * 64];
        acc = fmaf(e.x, w.x, acc);
        acc = fmaf(e.y, w.y, acc);
        acc = fmaf(e.z, w.z, acc);
        acc = fmaf(e.w, w.w, acc);
    }
    #pragma unroll
    for (int off = 32; off > 0; off >>= 1)
        acc += __shfl_down(acc, off);
    if (lane == 0) scores[b * T + t] = acc;
}

__global__ void __launch_bounds__(1024) softmax_kernel(
    const float* __restrict__ scores, float* __restrict__ out)
{
    int b = blockIdx.x;
    int tid = threadIdx.x;
    int wid = tid >> 6;
    int lane = tid & 63;
    __shared__ float redm[16];
    __shared__ float reds[16];

    const f4* rp = (const f4*)(scores + (size_t)b * T);
    f4 x = rp[tid];

    float m = fmaxf(fmaxf(x.x, x.y), fmaxf(x.z, x.w));
    #pragma unroll
    for (int off = 32; off > 0; off >>= 1)
        m = fmaxf(m, __shfl_xor(m, off));
    if (lane == 0) redm[wid] = m;
    __syncthreads();
    m = redm[0];
    #pragma unroll
    for (int i = 1; i < 16; ++i) m = fmaxf(m, redm[i]);

    x.x = __expf(x.x - m);
    x.y = __expf(x.y - m);
    x.z = __expf(x.z - m);
    x.w = __expf(x.w - m);
    float s = x.x + x.y + x.z + x.w;
    #pragma unroll
    for (int off = 32; off > 0; off >>= 1)
        s += __shfl_xor(s, off);
    if (lane == 0) reds[wid] = s;
    __syncthreads();
    s = reds[0];
    #pragma unroll
    for (int i = 1; i < 16; ++i) s += reds[i];
    float inv = 1.f / s;

    f4 r = x * inv;
    __builtin_nontemporal_store(r, (f4*)(out + (size_t)b * T) + tid);
}

extern "C" void kernel_launch(void* const* d_in, const int* in_sizes, int n_in,
                              void* d_out, int out_size, void* d_ws, size_t ws_size,
                              hipStream_t stream)
{
    const float* dec = (const float*)d_in[0];   // [H, B]
    const float* enc = (const float*)d_in[1];   // [T, B, H]
    const float* W   = (const float*)d_in[2];   // [H, H]
    float* out = (float*)d_out;                 // [B, T]

    float* v      = (float*)d_ws;               // B*H floats
    float* scores = v + B * H;                  // B*T floats

    void* args[] = {(void*)&dec, (void*)&enc, (void*)&W,
                    (void*)&v, (void*)&scores, (void*)&out};
    hipError_t err = hipLaunchCooperativeKernel(
        (const void*)fused_all, dim3(1024), dim3(256), args, 0, stream);

    if (err != hipSuccess) {
        // Deterministic fallback: proven 3-kernel path (52.3 us).
        proj_vec_kernel<<<512, 256, 0, stream>>>(dec, W, v);
        scores_kernel<<<(T * B) / 4, 256, 0, stream>>>(v, enc, scores);
        softmax_kernel<<<B, 1024, 0, stream>>>(scores, out);
    }
}

// Round 12
// 53.912 us; speedup vs baseline: 5.6058x; 5.2705x over previous
//
#include <hip/hip_runtime.h>
#include <math.h>

#define H 1024
#define T 4096
#define B 16

typedef float f4 __attribute__((ext_vector_type(4)));

// Kernel 1: v[b,h] = sum_d dec[d,b] * W[d,h]  (v = dec^T @ W, 16x1024)
// 512 blocks = 16 b x 32 htiles (32 h each); 2 blocks/CU -> 2 waves/SIMD.
__global__ void __launch_bounds__(256) proj_vec_kernel(
    const float* __restrict__ dec, const float* __restrict__ W,
    float* __restrict__ v)
{
    int b      = blockIdx.x >> 5;
    int htile  = blockIdx.x & 31;
    int h4     = threadIdx.x & 7;
    int dc     = threadIdx.x >> 3;
    int h4base = htile * 8;

    const f4* Wp = (const f4*)W;
    f4 acc = {0.f, 0.f, 0.f, 0.f};
    int d0 = dc * 32;
    #pragma unroll 8
    for (int i = 0; i < 32; ++i) {
        int d = d0 + i;
        float s = dec[d * B + b];
        f4 w = Wp[d * (H / 4) + h4base + h4];
        acc += s * w;
    }

    __shared__ f4 red[256];
    red[threadIdx.x] = acc;
    __syncthreads();
    #pragma unroll
    for (int s = 16; s > 0; s >>= 1) {
        if (dc < s) {
            f4 m = red[dc * 8 + h4] + red[(dc + s) * 8 + h4];
            red[dc * 8 + h4] = m;
        }
        __syncthreads();
    }
    if (dc == 0)
        ((f4*)(v + b * H))[h4base + h4] = red[h4];
}

// Kernel 2: scores[b,t] = dot(v[b,:], enc[t,b,:])  — proven R3/R7 shape.
// One 64-lane wave per (t,b); 4x f4 enc loads per lane; block of 4 waves
// covers 16 KiB contiguous. PLAIN (cached) loads: enc is 256 MiB = exactly
// Infinity-Cache size and timed replays don't re-poison inputs, so letting
// L3 retain enc lines raises the blended read rate (coop-run counters
// showed FETCH = 134 MB, i.e. half of enc already L3-served even with NT).
__global__ void __launch_bounds__(256) scores_kernel(
    const float* __restrict__ v, const float* __restrict__ enc,
    float* __restrict__ scores)
{
    int wave = (int)((blockIdx.x * 256u + threadIdx.x) >> 6);  // 0..65535
    int lane = threadIdx.x & 63;
    int b = wave & (B - 1);
    int t = wave >> 4;
    const f4* ep = (const f4*)(enc + (size_t)t * (B * H) + (size_t)b * H);
    const f4* vp = (const f4*)(v + b * H);
    float acc = 0.f;
    #pragma unroll
    for (int i = 0; i < 4; ++i) {
        f4 e = ep[lane + i * 64];
        f4 w = vp[lane + i * 64];
        acc = fmaf(e.x, w.x, acc);
        acc = fmaf(e.y, w.y, acc);
        acc = fmaf(e.z, w.z, acc);
        acc = fmaf(e.w, w.w, acc);
    }
    #pragma unroll
    for (int off = 32; off > 0; off >>= 1)
        acc += __shfl_down(acc, off);
    if (lane == 0) scores[b * T + t] = acc;
}

// Kernel 3: row softmax, one block of 1024 threads (16 waves) per b.
__global__ void __launch_bounds__(1024) softmax_kernel(
    const float* __restrict__ scores, float* __restrict__ out)
{
    int b = blockIdx.x;
    int tid = threadIdx.x;
    int wid = tid >> 6;
    int lane = tid & 63;
    __shared__ float redm[16];
    __shared__ float reds[16];

    const f4* rp = (const f4*)(scores + (size_t)b * T);
    f4 x = rp[tid];

    float m = fmaxf(fmaxf(x.x, x.y), fmaxf(x.z, x.w));
    #pragma unroll
    for (int off = 32; off > 0; off >>= 1)
        m = fmaxf(m, __shfl_xor(m, off));
    if (lane == 0) redm[wid] = m;
    __syncthreads();
    m = redm[0];
    #pragma unroll
    for (int i = 1; i < 16; ++i) m = fmaxf(m, redm[i]);

    x.x = __expf(x.x - m);
    x.y = __expf(x.y - m);
    x.z = __expf(x.z - m);
    x.w = __expf(x.w - m);
    float s = x.x + x.y + x.z + x.w;
    #pragma unroll
    for (int off = 32; off > 0; off >>= 1)
        s += __shfl_xor(s, off);
    if (lane == 0) reds[wid] = s;
    __syncthreads();
    s = reds[0];
    #pragma unroll
    for (int i = 1; i < 16; ++i) s += reds[i];
    float inv = 1.f / s;

    f4 r = x * inv;
    __builtin_nontemporal_store(r, (f4*)(out + (size_t)b * T) + tid);
}

extern "C" void kernel_launch(void* const* d_in, const int* in_sizes, int n_in,
                              void* d_out, int out_size, void* d_ws, size_t ws_size,
                              hipStream_t stream)
{
    const float* dec = (const float*)d_in[0];   // [H, B]
    const float* enc = (const float*)d_in[1];   // [T, B, H]
    const float* W   = (const float*)d_in[2];   // [H, H]
    float* out = (float*)d_out;                 // [B, T]

    float* v      = (float*)d_ws;               // B*H floats
    float* scores = v + B * H;                  // B*T floats

    proj_vec_kernel<<<512, 256, 0, stream>>>(dec, W, v);
    scores_kernel<<<(T * B) / 4, 256, 0, stream>>>(v, enc, scores);
    softmax_kernel<<<B, 1024, 0, stream>>>(scores, out);
}

// Round 13
// 52.297 us; speedup vs baseline: 5.7789x; 1.0309x over previous
//
#include <hip/hip_runtime.h>
#include <math.h>

#define H 1024
#define T 4096
#define B 16

typedef float f4 __attribute__((ext_vector_type(4)));

// ROOFLINE KERNEL (R7 config, 52.3 us measured):
//   scores stream = 268 MB / ~44 us = 6.1 TB/s = 97% of measured read ceiling.
//   Fusion (atomic x2, cooperative x2) all regressed; launch gaps ~3-4 us are
//   the irreducible remainder.

// Kernel 1: v[b,h] = sum_d dec[d,b] * W[d,h]  (v = dec^T @ W, 16x1024)
// 512 blocks = 16 b x 32 htiles (32 h each); 2 blocks/CU -> 2 waves/SIMD.
__global__ void __launch_bounds__(256) proj_vec_kernel(
    const float* __restrict__ dec, const float* __restrict__ W,
    float* __restrict__ v)
{
    int b      = blockIdx.x >> 5;
    int htile  = blockIdx.x & 31;
    int h4     = threadIdx.x & 7;
    int dc     = threadIdx.x >> 3;
    int h4base = htile * 8;

    const f4* Wp = (const f4*)W;
    f4 acc = {0.f, 0.f, 0.f, 0.f};
    int d0 = dc * 32;
    #pragma unroll 8
    for (int i = 0; i < 32; ++i) {
        int d = d0 + i;
        float s = dec[d * B + b];
        f4 w = Wp[d * (H / 4) + h4base + h4];
        acc += s * w;
    }

    __shared__ f4 red[256];
    red[threadIdx.x] = acc;
    __syncthreads();
    #pragma unroll
    for (int s = 16; s > 0; s >>= 1) {
        if (dc < s) {
            f4 m = red[dc * 8 + h4] + red[(dc + s) * 8 + h4];
            red[dc * 8 + h4] = m;
        }
        __syncthreads();
    }
    if (dc == 0)
        ((f4*)(v + b * H))[h4base + h4] = red[h4];
}

// Kernel 2: scores[b,t] = dot(v[b,:], enc[t,b,:]).
// One 64-lane wave per (t,b); 4x f4 NONTEMPORAL enc loads (measured: NT is
// ~1.6 us faster than plain — R7 vs R12 single-variable A/B); block of 4
// waves covers 16 KiB contiguous. Pure HBM stream at ~97% of read ceiling.
// Measured regressions to avoid: >1 row per wave concurrently (R4/R8),
// strided concurrent footprints (R10), atomic/coop fusion (R5/R6/R9-R11).
__global__ void __launch_bounds__(256) scores_kernel(
    const float* __restrict__ v, const float* __restrict__ enc,
    float* __restrict__ scores)
{
    int wave = (int)((blockIdx.x * 256u + threadIdx.x) >> 6);  // 0..65535
    int lane = threadIdx.x & 63;
    int b = wave & (B - 1);
    int t = wave >> 4;
    const f4* ep = (const f4*)(enc + (size_t)t * (B * H) + (size_t)b * H);
    const f4* vp = (const f4*)(v + b * H);
    float acc = 0.f;
    #pragma unroll
    for (int i = 0; i < 4; ++i) {
        f4 e = __builtin_nontemporal_load(&ep[lane + i * 64]);
        f4 w = vp[lane + i * 64];
        acc = fmaf(e.x, w.x, acc);
        acc = fmaf(e.y, w.y, acc);
        acc = fmaf(e.z, w.z, acc);
        acc = fmaf(e.w, w.w, acc);
    }
    #pragma unroll
    for (int off = 32; off > 0; off >>= 1)
        acc += __shfl_down(acc, off);
    if (lane == 0) scores[b * T + t] = acc;
}

// Kernel 3: row softmax, one block of 1024 threads (16 waves) per b.
__global__ void __launch_bounds__(1024) softmax_kernel(
    const float* __restrict__ scores, float* __restrict__ out)
{
    int b = blockIdx.x;
    int tid = threadIdx.x;
    int wid = tid >> 6;
    int lane = tid & 63;
    __shared__ float redm[16];
    __shared__ float reds[16];

    const f4* rp = (const f4*)(scores + (size_t)b * T);
    f4 x = rp[tid];

    float m = fmaxf(fmaxf(x.x, x.y), fmaxf(x.z, x.w));
    #pragma unroll
    for (int off = 32; off > 0; off >>= 1)
        m = fmaxf(m, __shfl_xor(m, off));
    if (lane == 0) redm[wid] = m;
    __syncthreads();
    m = redm[0];
    #pragma unroll
    for (int i = 1; i < 16; ++i) m = fmaxf(m, redm[i]);

    x.x = __expf(x.x - m);
    x.y = __expf(x.y - m);
    x.z = __expf(x.z - m);
    x.w = __expf(x.w - m);
    float s = x.x + x.y + x.z + x.w;
    #pragma unroll
    for (int off = 32; off > 0; off >>= 1)
        s += __shfl_xor(s, off);
    if (lane == 0) reds[wid] = s;
    __syncthreads();
    s = reds[0];
    #pragma unroll
    for (int i = 1; i < 16; ++i) s += reds[i];
    float inv = 1.f / s;

    f4 r = x * inv;
    __builtin_nontemporal_store(r, (f4*)(out + (size_t)b * T) + tid);
}

extern "C" void kernel_launch(void* const* d_in, const int* in_sizes, int n_in,
                              void* d_out, int out_size, void* d_ws, size_t ws_size,
                              hipStream_t stream)
{
    const float* dec = (const float*)d_in[0];   // [H, B]
    const float* enc = (const float*)d_in[1];   // [T, B, H]
    const float* W   = (const float*)d_in[2];   // [H, H]
    float* out = (float*)d_out;                 // [B, T]

    float* v      = (float*)d_ws;               // B*H floats
    float* scores = v + B * H;                  // B*T floats

    proj_vec_kernel<<<512, 256, 0, stream>>>(dec, W, v);
    scores_kernel<<<(T * B) / 4, 256, 0, stream>>>(v, enc, scores);
    softmax_kernel<<<B, 1024, 0, stream>>>(scores, out);
}